// Round 10
// baseline (261.550 us; speedup 1.0000x reference)
//
#include <hip/hip_runtime.h>
#include <hip/hip_bf16.h>
#include <cstddef>

// BS=8, NE=128, ENT=768, REL=768, RANK=256, OUT=256
// M = 131072 rows; rel row-major [b][i][j][768]
// ws: l1 [1024*256 f32] | l2 [1024*256 f32] | W3g [196608 bf16 frag] | Weg [65536 bf16 frag]
// Fragment-major B panels: flat = ((kq*256 + n)*4 + g)*8 + e (kq=k/32, g=(k/8)%4, e=k%8)
//
// fused_main K-loop (R9 + B register double-buffer, single barrier/iter):
//   iter ks: entry queue [B(ks), A(ks+1)]
//     issue B(ks+1) (L2-fast, first), A(ks+2) (HBM-slow, second)
//     barrier (Abuf dbuf handoff; no vmcnt drain)
//     MFMA tile ks: Br[ks&1] loaded ONE FULL ITERATION ago (B latency hidden);
//       compiler-counted vmcnt(16) retires B(ks) only
//     counted vmcnt(12) retires A(ks+1) -> ds_write to Abuf^1 -> lgkmcnt(0)
//   No vmcnt(0) anywhere in the loop; both streams get >= 1 iteration of window.

typedef __attribute__((ext_vector_type(8))) short short8;
typedef __attribute__((ext_vector_type(4))) float f32x4;

__device__ __forceinline__ unsigned short f2bf(float x) {
  union { float f; unsigned u; } v; v.f = x;
  unsigned r = (v.u + 0x7FFFu + ((v.u >> 16) & 1u)) >> 16;  // RNE
  return (unsigned short)r;
}
__device__ __forceinline__ unsigned short cvt1(float x) {
  return __bfloat16_as_ushort(__float2bfloat16(x));  // pairs to v_cvt_pk_bf16_f32
}
__device__ __forceinline__ f32x4 mfma16(short8 a, short8 b, f32x4 c) {
  return __builtin_amdgcn_mfma_f32_16x16x32_bf16(a, b, c, 0, 0, 0);
}
__device__ __forceinline__ short8 pk8(f32x4 x, f32x4 y) {
  short8 s;
  s[0] = (short)cvt1(x[0]); s[1] = (short)cvt1(x[1]);
  s[2] = (short)cvt1(x[2]); s[3] = (short)cvt1(x[3]);
  s[4] = (short)cvt1(y[0]); s[5] = (short)cvt1(y[1]);
  s[6] = (short)cvt1(y[2]); s[7] = (short)cvt1(y[3]);
  return s;
}

// ---------------- prep (grid 1280) -------------------------------------------
__global__ __launch_bounds__(256) void prep_all(
    const float* __restrict__ sub, const float* __restrict__ obj,
    const float* __restrict__ W1, const float* __restrict__ b1,
    const float* __restrict__ W2, const float* __restrict__ b2,
    const float* __restrict__ W3, const float* __restrict__ We,
    float* __restrict__ l1p, float* __restrict__ l2p,
    unsigned short* __restrict__ W3g, unsigned short* __restrict__ Weg) {
  const int tid = threadIdx.x;
  if (blockIdx.x >= 256) {
    int idx = (blockIdx.x - 256) * 256 + tid;
    if (idx < 196608) {
      int n = idx / 768, k = idx % 768;
      int f = ((k >> 5) * 256 + n) * 32 + ((k >> 3) & 3) * 8 + (k & 7);
      W3g[f] = f2bf(W3[idx]);
    }
    int j = idx - 196608;
    if (j >= 0 && j < 65536) {
      int n = j / 256, k = j % 256;
      int f = ((k >> 5) * 256 + n) * 32 + ((k >> 3) & 3) * 8 + (k & 7);
      Weg[f] = f2bf(We[j]);
    }
    return;
  }
  const int half = blockIdx.x >> 7;
  const float* x = half ? obj : sub;
  const float* W = half ? W2 : W1;
  const float* bias = half ? b2 : b1;
  float* outp = half ? l2p : l1p;

  __shared__ float xs[8][768];
  const int R0 = (blockIdx.x & 127) * 8;
  #pragma unroll
  for (int c = 0; c < 6; ++c) {
    int f4i = c * 256 + tid;
    int row = f4i / 192;
    int c4 = f4i % 192;
    *(float4*)&xs[row][c4 * 4] = *(const float4*)&x[(size_t)(R0 + row) * 768 + c4 * 4];
  }
  __syncthreads();
  const int col = tid;
  const float* Wr = W + (size_t)col * 768;
  float a[8] = {0.f, 0.f, 0.f, 0.f, 0.f, 0.f, 0.f, 0.f};
  for (int k4 = 0; k4 < 192; ++k4) {
    float4 wv = *(const float4*)&Wr[k4 * 4];
    #pragma unroll
    for (int r = 0; r < 8; ++r) {
      float4 xv = *(const float4*)&xs[r][k4 * 4];
      a[r] += wv.x * xv.x + wv.y * xv.y + wv.z * xv.z + wv.w * xv.w;
    }
  }
  float bb = bias[col];
  #pragma unroll
  for (int r = 0; r < 8; ++r)
    outp[(size_t)(R0 + r) * 256 + col] = a[r] + bb;
}

// ---------------- fused main -------------------------------------------------
__global__ __launch_bounds__(256, 3) void fused_main(
    const float* __restrict__ rel, const float* __restrict__ l1p,
    const float* __restrict__ l2p, const unsigned short* __restrict__ W3g,
    const unsigned short* __restrict__ Weg, const float* __restrict__ b3,
    const float* __restrict__ be, const float* __restrict__ lng,
    const float* __restrict__ lnb, float* __restrict__ out) {
  __shared__ union U {
    unsigned short stg[2][64][64];  // 16 KB bf16 staging (R2/R8 layout, clean)
    unsigned short prod[64][256];   // 32 KB
  } u;
  __shared__ float l1s[256], b3s[256], bes[256], gs[256], bsh[256];
  __shared__ float ps[64][4], pq[64][4], mus[64], rss[64];

  const int tid = threadIdx.x;
  const int wave = tid >> 6, lane = tid & 63;
  const int g = lane >> 4, c16 = lane & 15;

  // XCD-bijective swizzle (2048 % 8 == 0)
  const int bid = (blockIdx.x & 7) * 256 + (blockIdx.x >> 3);
  const int R0 = bid * 64;
  const int b = R0 >> 14;
  const int rem = R0 & 16383;
  const int i = rem >> 7;
  const int j0 = rem & 127;  // 0 or 64

  const float* relBase = rel + (size_t)((b * 128 + i) * 128 + j0) * 768;

  l1s[tid] = l1p[(b * 128 + i) * 256 + tid];
  b3s[tid] = b3[tid];
  bes[tid] = be[tid];
  gs[tid] = lng[tid];
  bsh[tid] = lnb[tid];

  // ---- staging geometry: wave owns rows wave*16 .. wave*16+15.
  // lane: row rr = wave*16 + (lane>>2), 16-f32 chunk c4 = lane&3.
  // LDS ushort row [64]: 8 units of 16B; write units (c4*2+h) ^ (rr&7).
  const int sr4 = lane >> 2, c4 = lane & 3;
  const int rr = wave * 16 + sr4;
  const float* aG = relBase + (size_t)rr * 768 + c4 * 16;
  unsigned short* stW0 = &u.stg[0][rr][((c4 * 2) ^ (rr & 7)) * 8];
  unsigned short* stW1 = &u.stg[0][rr][((c4 * 2 + 1) ^ (rr & 7)) * 8];

  // B: fragment-major W3g; n = wave*64 + fn*16 + c16
  const unsigned short* bp = W3g + (size_t)(wave * 64 + c16) * 32 + g * 8;

  f32x4 acc1[4][4] = {};
  f32x4 av[2][4];   // A prefetch data (2 generations, static idx via unroll)
  short8 Br[2][8];  // B fragments, double-buffered

#define SCHED0 __builtin_amdgcn_sched_barrier(0)
#define RAW_BARRIER                                           \
  do {                                                        \
    SCHED0;                                                   \
    asm volatile("s_waitcnt lgkmcnt(0)" ::: "memory");        \
    SCHED0;                                                   \
    __builtin_amdgcn_s_barrier();                             \
    SCHED0;                                                   \
  } while (0)

#define LOADB(DST, KS)                                                          \
  {                                                                             \
    _Pragma("unroll") for (int sub = 0; sub < 2; ++sub)                         \
        _Pragma("unroll") for (int fn = 0; fn < 4; ++fn)                        \
            DST[sub * 4 + fn] = *(const short8*)(bp + (size_t)((KS) * 2 + sub) * 8192 + fn * 512); \
  }

#define LOADA(DST, KS)                                                          \
  {                                                                             \
    const float* p_ = aG + (size_t)(KS) * 64;                                   \
    DST[0] = *(const f32x4*)(p_);                                               \
    DST[1] = *(const f32x4*)(p_ + 4);                                           \
    DST[2] = *(const f32x4*)(p_ + 8);                                           \
    DST[3] = *(const f32x4*)(p_ + 12);                                          \
  }

#define WRITEA(SRC, BUF)                                                        \
  {                                                                             \
    *(short8*)(stW0 + (BUF) * 4096) = pk8(SRC[0], SRC[1]);                      \
    *(short8*)(stW1 + (BUF) * 4096) = pk8(SRC[2], SRC[3]);                      \
  }

  // ---- prologue: B(0)->Br[0]; A(0) via av[1] temp -> Abuf0; A(1)->av[0]
  LOADB(Br[0], 0);
  LOADA(av[1], 0);
  LOADA(av[0], 1);
  SCHED0;
  WRITEA(av[1], 0);  // compiler: vmcnt(4) retires B0+A0, leaves A1 in flight
  RAW_BARRIER;

  #pragma unroll
  for (int ks = 0; ks < 12; ++ks) {
    const int buf = ks & 1;
    // issue next-gen loads: fast B first, slow A second (FIFO discipline)
    if (ks < 11) LOADB(Br[(ks + 1) & 1], ks + 1);
    if (ks <= 9) LOADA(av[(ks + 1) & 1], ks + 2);
    SCHED0;
    // compute tile ks: Br[buf] issued a full iteration ago; counted vmcnt only
    #pragma unroll
    for (int sub = 0; sub < 2; ++sub) {
      #pragma unroll
      for (int fm = 0; fm < 4; ++fm) {
        const int r = fm * 16 + c16;
        short8 ah = *(const short8*)&u.stg[buf][r][((sub * 4 + g) ^ (r & 7)) * 8];
        #pragma unroll
        for (int fn = 0; fn < 4; ++fn)
          acc1[fm][fn] = mfma16(ah, Br[buf][sub * 4 + fn], acc1[fm][fn]);
      }
    }
    SCHED0;
    // write A(ks+1) (counted vmcnt retires it; B(ks+1)/A(ks+2) stay in flight)
    if (ks <= 10) {
      WRITEA(av[ks & 1], (buf ^ 1));
      RAW_BARRIER;
    }
  }
  __syncthreads();  // queue empty; protects stg -> prod overlay

  // ---- epilogue 1: prod = (l3 + b3) * l1 * l2 -> bf16 swizzled LDS ----
  #pragma unroll
  for (int fm = 0; fm < 4; ++fm) {
    #pragma unroll
    for (int r = 0; r < 4; ++r) {
      const int m = fm * 16 + g * 4 + r;
      const float* l2row = l2p + (size_t)(b * 128 + j0 + m) * 256;
      #pragma unroll
      for (int fn = 0; fn < 4; ++fn) {
        const int col = wave * 64 + fn * 16 + c16;
        float v = (acc1[fm][fn][r] + b3s[col]) * l1s[col] * l2row[col];
        u.prod[m][col ^ ((m & 7) << 3)] = f2bf(v);
      }
    }
  }
  __syncthreads();

  // ---- GEMM2: f = prod @ Web^T (Weg fragment-major) ----
  f32x4 acc2[4][4] = {};
  #pragma unroll
  for (int kk = 0; kk < 8; ++kk) {
    short8 a2[4];
    #pragma unroll
    for (int fm = 0; fm < 4; ++fm) {
      const int m = fm * 16 + c16;
      a2[fm] = *(const short8*)&u.prod[m][(kk * 32 + g * 8) ^ ((m & 7) << 3)];
    }
    #pragma unroll
    for (int fn = 0; fn < 4; ++fn) {
      const int n = wave * 64 + fn * 16 + c16;
      short8 bfr = *(const short8*)&Weg[(size_t)((kk * 256 + n) * 4 + g) * 8];
      #pragma unroll
      for (int fm = 0; fm < 4; ++fm)
        acc2[fm][fn] = mfma16(a2[fm], bfr, acc2[fm][fn]);
    }
  }

  // ---- LN stats: per-row sum/sumsq; 16-lane shfl reduce + cross-wave LDS ----
  #pragma unroll
  for (int fm = 0; fm < 4; ++fm) {
    #pragma unroll
    for (int r = 0; r < 4; ++r) {
      float s1 = 0.f, s2 = 0.f;
      #pragma unroll
      for (int fn = 0; fn < 4; ++fn) {
        const int col = wave * 64 + fn * 16 + c16;
        float v = acc2[fm][fn][r] + bes[col];
        s1 += v; s2 += v * v;
      }
      #pragma unroll
      for (int off = 1; off < 16; off <<= 1) {
        s1 += __shfl_xor(s1, off);
        s2 += __shfl_xor(s2, off);
      }
      if (c16 == 0) {
        const int m = fm * 16 + g * 4 + r;
        ps[m][wave] = s1; pq[m][wave] = s2;
      }
    }
  }
  __syncthreads();
  if (tid < 64) {
    float s = ps[tid][0] + ps[tid][1] + ps[tid][2] + ps[tid][3];
    float q = pq[tid][0] + pq[tid][1] + pq[tid][2] + pq[tid][3];
    float mu = s * 0.00390625f;
    float var = q * 0.00390625f - mu * mu;
    mus[tid] = mu;
    rss[tid] = rsqrtf(var + 1e-6f);
  }
  __syncthreads();

  // ---- store: (f - mu)*rs*g + b ----
  #pragma unroll
  for (int fm = 0; fm < 4; ++fm) {
    #pragma unroll
    for (int r = 0; r < 4; ++r) {
      const int m = fm * 16 + g * 4 + r;
      const float mu = mus[m], rs = rss[m];
      float* orow = out + (size_t)(R0 + m) * 256;
      #pragma unroll
      for (int fn = 0; fn < 4; ++fn) {
        const int col = wave * 64 + fn * 16 + c16;
        float v = acc2[fm][fn][r] + bes[col];
        orow[col] = (v - mu) * rs * gs[col] + bsh[col];
      }
    }
  }
#undef SCHED0
#undef RAW_BARRIER
#undef LOADB
#undef LOADA
#undef WRITEA
}

extern "C" void kernel_launch(void* const* d_in, const int* in_sizes, int n_in,
                              void* d_out, int out_size, void* d_ws, size_t ws_size,
                              hipStream_t stream) {
  const float* sub = (const float*)d_in[0];
  const float* obj = (const float*)d_in[1];
  const float* rel = (const float*)d_in[2];
  const float* W1 = (const float*)d_in[3];
  const float* b1 = (const float*)d_in[4];
  const float* W2 = (const float*)d_in[5];
  const float* b2 = (const float*)d_in[6];
  const float* W3 = (const float*)d_in[7];
  const float* b3 = (const float*)d_in[8];
  const float* We = (const float*)d_in[9];
  const float* be = (const float*)d_in[10];
  const float* lng = (const float*)d_in[11];
  const float* lnb = (const float*)d_in[12];
  float* out = (float*)d_out;

  float* ws = (float*)d_ws;
  float* l1p = ws;
  float* l2p = ws + 262144;
  unsigned short* W3g = (unsigned short*)(ws + 524288);
  unsigned short* Weg = W3g + 196608;

  prep_all<<<1280, 256, 0, stream>>>(sub, obj, W1, b1, W2, b2, W3, We, l1p, l2p, W3g, Weg);
  fused_main<<<2048, 256, 0, stream>>>(rel, l1p, l2p, W3g, Weg, b3, be, lng, lnb, out);
}

// Round 11
// 216.489 us; speedup vs baseline: 1.2081x; 1.2081x over previous
//
#include <hip/hip_runtime.h>
#include <hip/hip_bf16.h>
#include <cstddef>

// BS=8, NE=128, ENT=768, REL=768, RANK=256, OUT=256
// M = 131072 rows; rel row-major [b][i][j][768]
// ws: l1 [1024*256 f32] | l2 [1024*256 f32] | W3g [196608 bf16 frag] | Weg [65536 bf16 frag]
// Fragment-major B panels: flat = ((kq*256 + n)*4 + g)*8 + e (kq=k/32, g=(k/8)%4, e=k%8)
//
// fused_main R11:
//  - 4 blocks/CU (LDS 34.5 KB, VGPR<=128 via launch_bounds(256,4)): the R3-R10
//    cluster was stuck at 3 blocks (LDS 40448 -> 3.96) and ~12 waves.
//  - A(rel) staged f32 via global_load_lds, FULL 16-unit XOR swizzle:
//    LDS[r][u] = G[r][u ^ (r&15)] (R3/R7 only XOR'd even units -> 44M conflicts).
//    bf16 cvt at fragment-read time (v_cvt_pk).
//  - B(W3g) single-buffer regs, loaded FIRST each iter; stage(k+1) second;
//    waits: vmcnt(12)=retire stage(k); barrier; vmcnt(4)=retire B(k) (stage(k+1)
//    stays in flight); MFMA; barrier. vmcnt(0) only at the last tile.
//  - small vectors (l1,b3,be,ln_g,ln_b) read direct from L2 (no LDS mirrors).

typedef __attribute__((ext_vector_type(8))) short short8;
typedef __attribute__((ext_vector_type(4))) float f32x4;

__device__ __forceinline__ unsigned short f2bf(float x) {
  union { float f; unsigned u; } v; v.f = x;
  unsigned r = (v.u + 0x7FFFu + ((v.u >> 16) & 1u)) >> 16;  // RNE
  return (unsigned short)r;
}
__device__ __forceinline__ unsigned short cvt1(float x) {
  return __bfloat16_as_ushort(__float2bfloat16(x));  // pairs to v_cvt_pk_bf16_f32
}
__device__ __forceinline__ f32x4 mfma16(short8 a, short8 b, f32x4 c) {
  return __builtin_amdgcn_mfma_f32_16x16x32_bf16(a, b, c, 0, 0, 0);
}
__device__ __forceinline__ short8 pk8(f32x4 x, f32x4 y) {
  short8 s;
  s[0] = (short)cvt1(x[0]); s[1] = (short)cvt1(x[1]);
  s[2] = (short)cvt1(x[2]); s[3] = (short)cvt1(x[3]);
  s[4] = (short)cvt1(y[0]); s[5] = (short)cvt1(y[1]);
  s[6] = (short)cvt1(y[2]); s[7] = (short)cvt1(y[3]);
  return s;
}
__device__ __forceinline__ void gload_lds16(const float* g, float* l) {
  __builtin_amdgcn_global_load_lds((__attribute__((address_space(1))) void*)(g),
                                   (__attribute__((address_space(3))) void*)(l), 16, 0, 0);
}

// ---------------- prep (grid 1280) -------------------------------------------
__global__ __launch_bounds__(256) void prep_all(
    const float* __restrict__ sub, const float* __restrict__ obj,
    const float* __restrict__ W1, const float* __restrict__ b1,
    const float* __restrict__ W2, const float* __restrict__ b2,
    const float* __restrict__ W3, const float* __restrict__ We,
    float* __restrict__ l1p, float* __restrict__ l2p,
    unsigned short* __restrict__ W3g, unsigned short* __restrict__ Weg) {
  const int tid = threadIdx.x;
  if (blockIdx.x >= 256) {
    int idx = (blockIdx.x - 256) * 256 + tid;
    if (idx < 196608) {
      int n = idx / 768, k = idx % 768;
      int f = ((k >> 5) * 256 + n) * 32 + ((k >> 3) & 3) * 8 + (k & 7);
      W3g[f] = f2bf(W3[idx]);
    }
    int j = idx - 196608;
    if (j >= 0 && j < 65536) {
      int n = j / 256, k = j % 256;
      int f = ((k >> 5) * 256 + n) * 32 + ((k >> 3) & 3) * 8 + (k & 7);
      Weg[f] = f2bf(We[j]);
    }
    return;
  }
  const int half = blockIdx.x >> 7;
  const float* x = half ? obj : sub;
  const float* W = half ? W2 : W1;
  const float* bias = half ? b2 : b1;
  float* outp = half ? l2p : l1p;

  __shared__ float xs[8][768];
  const int R0 = (blockIdx.x & 127) * 8;
  #pragma unroll
  for (int c = 0; c < 6; ++c) {
    int f4i = c * 256 + tid;
    int row = f4i / 192;
    int c4 = f4i % 192;
    *(float4*)&xs[row][c4 * 4] = *(const float4*)&x[(size_t)(R0 + row) * 768 + c4 * 4];
  }
  __syncthreads();
  const int col = tid;
  const float* Wr = W + (size_t)col * 768;
  float a[8] = {0.f, 0.f, 0.f, 0.f, 0.f, 0.f, 0.f, 0.f};
  for (int k4 = 0; k4 < 192; ++k4) {
    float4 wv = *(const float4*)&Wr[k4 * 4];
    #pragma unroll
    for (int r = 0; r < 8; ++r) {
      float4 xv = *(const float4*)&xs[r][k4 * 4];
      a[r] += wv.x * xv.x + wv.y * xv.y + wv.z * xv.z + wv.w * xv.w;
    }
  }
  float bb = bias[col];
  #pragma unroll
  for (int r = 0; r < 8; ++r)
    outp[(size_t)(R0 + r) * 256 + col] = a[r] + bb;
}

// ---------------- fused main -------------------------------------------------
__global__ __launch_bounds__(256, 4) void fused_main(
    const float* __restrict__ rel, const float* __restrict__ l1p,
    const float* __restrict__ l2p, const unsigned short* __restrict__ W3g,
    const unsigned short* __restrict__ Weg, const float* __restrict__ b3,
    const float* __restrict__ be, const float* __restrict__ lng,
    const float* __restrict__ lnb, float* __restrict__ out) {
  __shared__ union U {
    float stgf[2][64][64];          // 32 KB f32 staging, 16-unit XOR swizzle
    unsigned short prod[64][256];   // 32 KB
  } u;
  __shared__ float ps[64][4], pq[64][4], mus[64], rss[64];  // 2.5 KB

  const int tid = threadIdx.x;
  const int wave = tid >> 6, lane = tid & 63;
  const int g = lane >> 4, c16 = lane & 15;

  // XCD-bijective swizzle (2048 % 8 == 0)
  const int bid = (blockIdx.x & 7) * 256 + (blockIdx.x >> 3);
  const int R0 = bid * 64;
  const int b = R0 >> 14;
  const int rem = R0 & 16383;
  const int i = rem >> 7;
  const int j0 = rem & 127;  // 0 or 64

  const float* relBase = rel + (size_t)((b * 128 + i) * 128 + j0) * 768;

  // ---- staging geometry: wave covers rows wave*16..+15 in 4 gload_lds.
  // instr q: rows wave*16+q*4 .. +3; lane l: row +(l>>4), dst unit l&15,
  // src unit = (l&15) ^ (r&15).
  const int rq = lane >> 4;   // row within 4-row chunk
  const int udst = lane & 15;
  const float* gsrc[4];
  #pragma unroll
  for (int q = 0; q < 4; ++q) {
    int rlow = q * 4 + rq;  // r & 15 (wave*16 is 0 mod 16)
    gsrc[q] = relBase + (size_t)(wave * 16 + rlow) * 768 + ((udst ^ rlow) * 4);
  }

#define ISSUE(BUF, KS)                                                         \
  {                                                                            \
    _Pragma("unroll") for (int q = 0; q < 4; ++q)                              \
        gload_lds16(gsrc[q] + (KS) * 64, &u.stgf[BUF][wave * 16 + q * 4][0]);  \
  }

  // B: fragment-major W3g; n = wave*64 + fn*16 + c16
  const unsigned short* bp = W3g + (size_t)(wave * 64 + c16) * 32 + g * 8;
  short8 Br[8];

#define LOADB(KS)                                                              \
  {                                                                            \
    _Pragma("unroll") for (int sub = 0; sub < 2; ++sub)                        \
        _Pragma("unroll") for (int fn = 0; fn < 4; ++fn)                       \
            Br[sub * 4 + fn] = *(const short8*)(bp + (size_t)((KS) * 2 + sub) * 8192 + fn * 512); \
  }

  f32x4 acc1[4][4] = {};

#define SCHED0 __builtin_amdgcn_sched_barrier(0)

  // prologue: stage(0) -> buf0
  ISSUE(0, 0);

  #pragma unroll
  for (int ks = 0; ks < 12; ++ks) {
    const int buf = ks & 1;
    LOADB(ks);                                   // 8 fast L2 loads
    SCHED0;
    if (ks < 11) ISSUE(buf ^ 1, ks + 1);         // 4 slow HBM gload_lds
    SCHED0;
    if (ks < 11) {
      asm volatile("s_waitcnt vmcnt(12)" ::: "memory");  // retire stage(ks)
    } else {
      asm volatile("s_waitcnt vmcnt(8)" ::: "memory");
    }
    SCHED0;
    __builtin_amdgcn_s_barrier();                // all waves' stage(ks) landed
    SCHED0;
    if (ks < 11) {
      asm volatile("s_waitcnt vmcnt(4)" ::: "memory");   // retire B(ks); stage(ks+1) in flight
    } else {
      asm volatile("s_waitcnt vmcnt(0)" ::: "memory");
    }
    SCHED0;
    // compute tile ks: read f32 pairs from swizzled LDS, cvt, MFMA
    #pragma unroll
    for (int sub = 0; sub < 2; ++sub) {
      #pragma unroll
      for (int fm = 0; fm < 4; ++fm) {
        const float* rowp = &u.stgf[buf][fm * 16 + c16][0];
        const int ub = sub * 8 + g * 2;
        f32x4 lo = *(const f32x4*)(rowp + ((ub ^ c16) * 4));
        f32x4 hi = *(const f32x4*)(rowp + (((ub + 1) ^ c16) * 4));
        short8 ah = pk8(lo, hi);
        #pragma unroll
        for (int fn = 0; fn < 4; ++fn)
          acc1[fm][fn] = mfma16(ah, Br[sub * 4 + fn], acc1[fm][fn]);
      }
    }
    SCHED0;
    asm volatile("s_waitcnt lgkmcnt(0)" ::: "memory");
    SCHED0;
    __builtin_amdgcn_s_barrier();                // release buf for stage(ks+2)
    SCHED0;
  }

  // ---- epilogue 1: prod = (l3 + b3) * l1 * l2 -> bf16 swizzled LDS ----
  const int colb = wave * 64 + c16;
  const float* l1row = l1p + (size_t)(b * 128 + i) * 256;
  float l1v[4], b3v[4];
  #pragma unroll
  for (int fn = 0; fn < 4; ++fn) {
    l1v[fn] = l1row[colb + fn * 16];
    b3v[fn] = b3[colb + fn * 16];
  }
  #pragma unroll
  for (int fm = 0; fm < 4; ++fm) {
    #pragma unroll
    for (int r = 0; r < 4; ++r) {
      const int m = fm * 16 + g * 4 + r;
      const float* l2row = l2p + (size_t)(b * 128 + j0 + m) * 256;
      #pragma unroll
      for (int fn = 0; fn < 4; ++fn) {
        float v = (acc1[fm][fn][r] + b3v[fn]) * l1v[fn] * l2row[colb + fn * 16];
        u.prod[m][(colb + fn * 16) ^ ((m & 7) << 3)] = f2bf(v);
      }
    }
  }
  __syncthreads();

  // ---- GEMM2: f = prod @ Web^T (Weg fragment-major) ----
  f32x4 acc2[4][4] = {};
  #pragma unroll
  for (int kk = 0; kk < 8; ++kk) {
    short8 a2[4];
    #pragma unroll
    for (int fm = 0; fm < 4; ++fm) {
      const int m = fm * 16 + c16;
      a2[fm] = *(const short8*)&u.prod[m][(kk * 32 + g * 8) ^ ((m & 7) << 3)];
    }
    #pragma unroll
    for (int fn = 0; fn < 4; ++fn) {
      const int n = wave * 64 + fn * 16 + c16;
      short8 bfr = *(const short8*)&Weg[(size_t)((kk * 256 + n) * 4 + g) * 8];
      #pragma unroll
      for (int fm = 0; fm < 4; ++fm)
        acc2[fm][fn] = mfma16(a2[fm], bfr, acc2[fm][fn]);
    }
  }

  // ---- LN stats: per-row sum/sumsq; 16-lane shfl reduce + cross-wave LDS ----
  float bev[4];
  #pragma unroll
  for (int fn = 0; fn < 4; ++fn) bev[fn] = be[colb + fn * 16];
  #pragma unroll
  for (int fm = 0; fm < 4; ++fm) {
    #pragma unroll
    for (int r = 0; r < 4; ++r) {
      float s1 = 0.f, s2 = 0.f;
      #pragma unroll
      for (int fn = 0; fn < 4; ++fn) {
        float v = acc2[fm][fn][r] + bev[fn];
        s1 += v; s2 += v * v;
      }
      #pragma unroll
      for (int off = 1; off < 16; off <<= 1) {
        s1 += __shfl_xor(s1, off);
        s2 += __shfl_xor(s2, off);
      }
      if (c16 == 0) {
        const int m = fm * 16 + g * 4 + r;
        ps[m][wave] = s1; pq[m][wave] = s2;
      }
    }
  }
  __syncthreads();
  if (tid < 64) {
    float s = ps[tid][0] + ps[tid][1] + ps[tid][2] + ps[tid][3];
    float q = pq[tid][0] + pq[tid][1] + pq[tid][2] + pq[tid][3];
    float mu = s * 0.00390625f;
    float var = q * 0.00390625f - mu * mu;
    mus[tid] = mu;
    rss[tid] = rsqrtf(var + 1e-6f);
  }
  __syncthreads();

  // ---- store: (f - mu)*rs*g + b ----
  float gv[4], bhv[4];
  #pragma unroll
  for (int fn = 0; fn < 4; ++fn) {
    gv[fn] = lng[colb + fn * 16];
    bhv[fn] = lnb[colb + fn * 16];
  }
  #pragma unroll
  for (int fm = 0; fm < 4; ++fm) {
    #pragma unroll
    for (int r = 0; r < 4; ++r) {
      const int m = fm * 16 + g * 4 + r;
      const float mu = mus[m], rs = rss[m];
      float* orow = out + (size_t)(R0 + m) * 256;
      #pragma unroll
      for (int fn = 0; fn < 4; ++fn) {
        float v = acc2[fm][fn][r] + bev[fn];
        orow[colb + fn * 16] = (v - mu) * rs * gv[fn] + bhv[fn];
      }
    }
  }
#undef ISSUE
#undef LOADB
#undef SCHED0
}

extern "C" void kernel_launch(void* const* d_in, const int* in_sizes, int n_in,
                              void* d_out, int out_size, void* d_ws, size_t ws_size,
                              hipStream_t stream) {
  const float* sub = (const float*)d_in[0];
  const float* obj = (const float*)d_in[1];
  const float* rel = (const float*)d_in[2];
  const float* W1 = (const float*)d_in[3];
  const float* b1 = (const float*)d_in[4];
  const float* W2 = (const float*)d_in[5];
  const float* b2 = (const float*)d_in[6];
  const float* W3 = (const float*)d_in[7];
  const float* b3 = (const float*)d_in[8];
  const float* We = (const float*)d_in[9];
  const float* be = (const float*)d_in[10];
  const float* lng = (const float*)d_in[11];
  const float* lnb = (const float*)d_in[12];
  float* out = (float*)d_out;

  float* ws = (float*)d_ws;
  float* l1p = ws;
  float* l2p = ws + 262144;
  unsigned short* W3g = (unsigned short*)(ws + 524288);
  unsigned short* Weg = W3g + 196608;

  prep_all<<<1280, 256, 0, stream>>>(sub, obj, W1, b1, W2, b2, W3, We, l1p, l2p, W3g, Weg);
  fused_main<<<2048, 256, 0, stream>>>(rel, l1p, l2p, W3g, Weg, b3, be, lng, lnb, out);
}